// Round 6
// baseline (714.172 us; speedup 1.0000x reference)
//
#include <hip/hip_runtime.h>
#include <math.h>

#define BN_SCALE 0.9999950000374997f

typedef unsigned short u16;
typedef short bfrag8 __attribute__((ext_vector_type(8)));
typedef float floatx4 __attribute__((ext_vector_type(4)));

struct ushort4_t { u16 x, y, z, w; };

__device__ __forceinline__ u16 f2bf(float f) {
  union { float f; unsigned u; } c; c.f = f;
  unsigned r = c.u + 0x7FFFu + ((c.u >> 16) & 1u);
  return (u16)(r >> 16);
}

__device__ __forceinline__ void gload_lds16(const u16* g, u16* l) {
  __builtin_amdgcn_global_load_lds(
      (const __attribute__((address_space(1))) void*)g,
      (__attribute__((address_space(3))) void*)l, 16, 0, 0);
}

__device__ __forceinline__ floatx4 mfma16(bfrag8 a, bfrag8 b, floatx4 c) {
  return __builtin_amdgcn_mfma_f32_16x16x32_bf16(a, b, c, 0, 0, 0);
}

// qB/kB layout (u16): [n][tile(48)][kk(8)][row(192)][col(64)]
//   offset = ((n*48+tile)*8 + kk)*12288 + row*64 + col
// Stored UNswizzled; consumers stage with swizzled source chunk (cc ^= row&7).

// ---------------- K0: prep — gate sigmoid, w1->bf16, w2*alpha->bf16, beta2 ---------
__global__ void k_prep(const float* __restrict__ se, float* __restrict__ gate,
                       const float* __restrict__ w1, u16* __restrict__ w1B,
                       const float* __restrict__ w2, const float* __restrict__ g2,
                       const float* __restrict__ b2, const float* __restrict__ bb2,
                       u16* __restrict__ w2B, float* __restrict__ beta2) {
  int idx = blockIdx.x * 256 + threadIdx.x;
  if (idx < 110592) {
    float x = se[idx];
    gate[idx] = 1.0f / (1.0f + expf(-x));
    return;
  }
  idx -= 110592;
  if (idx < 786432) {
    w1B[idx] = f2bf(w1[idx]);
    return;
  }
  idx -= 786432;
  if (idx < 1179648) {
    int nf = idx / 192;  // n*2048 + f
    w2B[idx] = f2bf(w2[idx] * (g2[nf] * BN_SCALE));
    return;
  }
  idx -= 1179648;
  if (idx < 6144) beta2[idx] = b2[idx] * (g2[idx] * BN_SCALE) + bb2[idx];
}

// ---------------- K2: fc1 GEMM  (f32 A converted inline, bf16 w1B staged async) -----
// Tile 128 rows x 256 cols, BK=64. Output -> kk-tiled qB/kB layout above.
__global__ __launch_bounds__(256, 2) void k_fc1(
    const float* __restrict__ memin, const float* __restrict__ featin,
    const u16* __restrict__ w1B, const float* __restrict__ b1,
    u16* __restrict__ qB, u16* __restrict__ kB) {
  __shared__ __align__(16) u16 At[128 * 64];
  __shared__ __align__(16) u16 Bt[256 * 64];
  const int tid = threadIdx.x, lane = tid & 63, wave = tid >> 6;
  const int bz = blockIdx.z, n = bz >> 1, side = bz & 1;
  const int m0 = blockIdx.y * 128, n0 = blockIdx.x * 256;
  const float* A = (side ? featin : memin) + n * 512;   // ld 1536 f32
  const u16* B = w1B + (size_t)n * 262144;              // ld 512 bf16
  u16* Cn = (side ? kB : qB) + (size_t)n * 4718592;

  floatx4 acc[4][8];
  for (int i = 0; i < 4; i++)
    for (int j = 0; j < 8; j++) acc[i][j] = (floatx4){0.f, 0.f, 0.f, 0.f};
  const int wr = wave >> 1, wc = wave & 1;
  const int lr = lane & 15, lq = lane >> 4;
  const int sw = lr & 7;
  const int cc0 = (lq ^ sw) << 3, cc1 = ((lq + 4) ^ sw) << 3;

  for (int kk = 0; kk < 8; ++kk) {
    const int k0 = kk * 64;
    __syncthreads();
    // A: f32 -> bf16, source-swizzled chunk (8 f32 -> one 16B LDS chunk)
    for (int it = 0; it < 4; ++it) {
      int ch = it * 256 + tid;              // chunk in 128x64 tile
      int row = ch >> 3, cc = ch & 7;
      int scc = cc ^ (row & 7);
      const float* src = &A[(size_t)(m0 + row) * 1536 + k0 + scc * 8];
      float4 a0 = *(const float4*)src;
      float4 a1 = *(const float4*)(src + 4);
      ushort4_t h0 = {f2bf(a0.x), f2bf(a0.y), f2bf(a0.z), f2bf(a0.w)};
      ushort4_t h1 = {f2bf(a1.x), f2bf(a1.y), f2bf(a1.z), f2bf(a1.w)};
      *(ushort4_t*)&At[ch * 8] = h0;
      *(ushort4_t*)&At[ch * 8 + 4] = h1;
    }
    // B: bf16 async staging, source-swizzled
    for (int it = 0; it < 8; ++it) {
      int chb = it * 256 + wave * 64;
      int ch = chb + lane;
      int row = ch >> 3, cc = ch & 7;
      int scc = cc ^ (row & 7);
      gload_lds16(B + (size_t)(n0 + row) * 512 + k0 + scc * 8, &Bt[chb * 8]);
    }
    __syncthreads();
#pragma unroll
    for (int k2 = 0; k2 < 2; ++k2) {
      const int cco = k2 ? cc1 : cc0;
      bfrag8 a[4], b[8];
      for (int i = 0; i < 4; i++)
        a[i] = *(const bfrag8*)&At[(wr * 64 + i * 16 + lr) * 64 + cco];
      for (int j = 0; j < 8; j++)
        b[j] = *(const bfrag8*)&Bt[(wc * 128 + j * 16 + lr) * 64 + cco];
      for (int i = 0; i < 4; i++)
        for (int j = 0; j < 8; j++) acc[i][j] = mfma16(a[i], b[j], acc[i][j]);
    }
  }
  for (int j = 0; j < 8; j++) {
    int col = n0 + wc * 128 + j * 16 + lr;
    float bias = b1[n * 512 + col];
    int kkd = col >> 6, cw = col & 63;
    for (int i = 0; i < 4; i++) {
      int rbase = m0 + wr * 64 + i * 16 + lq * 4;
      for (int rg = 0; rg < 4; rg++) {
        int rr = rbase + rg;
        int tile = rr / 192, rw = rr - tile * 192;
        Cn[((size_t)tile * 8 + kkd) * 12288 + rw * 64 + cw] =
            f2bf(acc[i][j][rg] + bias);
      }
    }
  }
}

// ---------------- K3: per (n,q,kpair): two gated 192x192 tiles + dual max-pool ------
// 8 waves: ws=wave>>1 in [0,4) over s=384 (2 k-tiles), wt=wave&1 over t=192.
// Double-buffered dynamic LDS: 2 bufs x 3 sub-tiles (A0,A1,B) x 24576B = 147456 B.
// Each stage: 3 tiles x 1536 chunks = 4608 chunk-loads = 9 it x 512 threads.
__global__ __launch_bounds__(512, 2) void k_score(
    const u16* __restrict__ qB, const u16* __restrict__ kB,
    const float* __restrict__ gate,
    const float* __restrict__ bn1g, const float* __restrict__ bn1b,
    u16* __restrict__ pooled) {
  extern __shared__ __align__(16) u16 SH[];  // [buf][tsel][12288]
  const int tid = threadIdx.x, lane = tid & 63, wave = tid >> 6;
  const int lin = blockIdx.x, n = blockIdx.y;
  const int xcd = lin & 7, idx = lin >> 3;      // idx in [0,144)
  const int qIdx = idx / 3, kp = xcd * 3 + (idx - (idx / 3) * 3);
  const int kIdx0 = kp * 2;
  const int ws = wave >> 1, wt = wave & 1;
  const int lr = lane & 15, lq = lane >> 4;
  const int sw = lr & 7;
  const int cc0 = (lq ^ sw) << 3, cc1 = ((lq + 4) ^ sw) << 3;

  const u16* Ak0 = kB + ((size_t)(n * 48 + kIdx0) * 8) * 12288;
  const u16* Ak1 = kB + ((size_t)(n * 48 + kIdx0 + 1) * 8) * 12288;
  const u16* Bq = qB + ((size_t)(n * 48 + qIdx) * 8) * 12288;

  floatx4 acc[6][6];
  for (int i = 0; i < 6; i++)
    for (int j = 0; j < 6; j++) acc[i][j] = (floatx4){0.f, 0.f, 0.f, 0.f};

  // ---- staging: it/3 selects tile (A0,A1,B); (it%3)*512+wave*64+lane is chunk ----
#define STAGE(KK, BUF)                                                        \
  {                                                                           \
    const int kkq = (KK);                                                     \
    for (int it = 0; it < 9; ++it) {                                          \
      int tsel = it / 3;                                                      \
      int lcb = (it - tsel * 3) * 512 + wave * 64;                            \
      int lc = lcb + lane;                                                    \
      int row = lc >> 3, cc = lc & 7;                                         \
      int scc = cc ^ (row & 7);                                               \
      const u16* base = tsel == 0 ? Ak0 : (tsel == 1 ? Ak1 : Bq);             \
      gload_lds16(base + kkq * 12288 + row * 64 + scc * 8,                    \
                  SH + ((BUF) * 3 + tsel) * 12288 + lcb * 8);                 \
    }                                                                         \
  }

  STAGE(0, 0);
  for (int kk = 0; kk < 8; ++kk) {
    __syncthreads();  // drains staging of kk (issued last iter / preloop)
    if (kk < 7) STAGE(kk + 1, (kk + 1) & 1);
    const u16* SHa = SH + (((kk & 1) * 3) + (ws >> 1)) * 12288;
    const u16* SHb = SH + (((kk & 1) * 3) + 2) * 12288;
#pragma unroll
    for (int k2 = 0; k2 < 2; ++k2) {
      const int cco = k2 ? cc1 : cc0;
      bfrag8 a[6], b[6];
      for (int i = 0; i < 6; i++)
        a[i] = *(const bfrag8*)&SHa[((ws & 1) * 96 + i * 16 + lr) * 64 + cco];
      for (int j = 0; j < 6; j++)
        b[j] = *(const bfrag8*)&SHb[(wt * 96 + j * 16 + lr) * 64 + cco];
      for (int i = 0; i < 6; i++)
        for (int j = 0; j < 6; j++) acc[i][j] = mfma16(a[i], b[j], acc[i][j]);
    }
  }
#undef STAGE

  // ---- gated dual max-pool ----
  const float* gaten = gate + (size_t)n * 36864;
  float colp[6], rowp[6][4];
  for (int j = 0; j < 6; j++) colp[j] = -INFINITY;
  for (int i = 0; i < 6; i++)
    for (int rg = 0; rg < 4; rg++) rowp[i][rg] = -INFINITY;
  for (int i = 0; i < 6; i++) {
    for (int j = 0; j < 6; j++) {
      int t = wt * 96 + j * 16 + lr;
      for (int rg = 0; rg < 4; rg++) {
        int sl = (ws & 1) * 96 + i * 16 + lq * 4 + rg;  // s within k-tile
        float v = acc[i][j][rg] * gaten[sl * 192 + t];
        colp[j] = fmaxf(colp[j], v);
        rowp[i][rg] = fmaxf(rowp[i][rg], v);
      }
    }
  }
  __syncthreads();  // done with SH as tiles; reuse as reduction scratch
  float* colL = (float*)SH;                 // [16][192]  (12288 B)
  float* rowL = (float*)(SH + 8192);        // [2][384]   (3072 B, byte off 16384)
  for (int j = 0; j < 6; j++)
    colL[(ws * 4 + lq) * 192 + wt * 96 + j * 16 + lr] = colp[j];
  for (int i = 0; i < 6; i++)
    for (int rg = 0; rg < 4; rg++) {
      float v = rowp[i][rg];
      v = fmaxf(v, __shfl_xor(v, 1));
      v = fmaxf(v, __shfl_xor(v, 2));
      v = fmaxf(v, __shfl_xor(v, 4));
      v = fmaxf(v, __shfl_xor(v, 8));
      if (lr == 0) rowL[wt * 384 + ws * 96 + i * 16 + lq * 4 + rg] = v;
    }
  __syncthreads();

  const float g1 = bn1g[n] * BN_SCALE;
  const float bb1 = bn1b[n];
  for (int id = tid; id < 768; id += 512) {
    int c = id / 384, r = id - c * 384;
    float m;
    if (r < 192) {
      m = colL[(c * 8) * 192 + r];
      for (int w = 1; w < 8; w++) m = fmaxf(m, colL[(c * 8 + w) * 192 + r]);
    } else {
      int sg = c * 192 + (r - 192);
      m = fmaxf(rowL[sg], rowL[384 + sg]);
    }
    pooled[((size_t)n * 2304 + (size_t)qIdx * 48 + kIdx0 + c) * 384 + r] =
        f2bf(m * g1 + bb1);
  }
}

// ---------------- K4: fused fc2(alpha-folded) + relu + fc3 partials ----------------
__global__ __launch_bounds__(256, 1) void k_mlp(
    const u16* __restrict__ pooled, const u16* __restrict__ w2B,
    const float* __restrict__ beta2, const float* __restrict__ w3,
    float* __restrict__ r) {
  __shared__ __align__(16) u16 Xt[128 * 64];
  __shared__ __align__(16) u16 Wt[128 * 64];
  const int tid = threadIdx.x, lane = tid & 63, wave = tid >> 6;
  const int n = blockIdx.z, row0 = blockIdx.y * 128, f0 = blockIdx.x * 512;
  const u16* X = pooled + ((size_t)n * 4608 + row0) * 192;  // ld 192 bf16
  const u16* W = w2B + (size_t)n * 2048 * 192;              // ld 192 bf16
  const int wr = wave >> 1, wc = wave & 1;
  const int lr = lane & 15, lq = lane >> 4;
  const int sw = lr & 7;
  const int cc0 = (lq ^ sw) << 3, cc1 = ((lq + 4) ^ sw) << 3;
  float rp[4][4];
  for (int i = 0; i < 4; i++)
    for (int rg = 0; rg < 4; rg++) rp[i][rg] = 0.f;

  for (int fs = 0; fs < 4; ++fs) {
    const int fb = f0 + fs * 128;
    floatx4 acc[4][4];
    for (int i = 0; i < 4; i++)
      for (int j = 0; j < 4; j++) acc[i][j] = (floatx4){0.f, 0.f, 0.f, 0.f};
    for (int kk = 0; kk < 3; ++kk) {
      const int k0 = kk * 64;
      __syncthreads();
      for (int it = 0; it < 4; ++it) {
        int chb = it * 256 + wave * 64;
        int ch = chb + lane;
        int row = ch >> 3, cc = ch & 7;
        int scc = (cc ^ (row & 7)) << 3;
        gload_lds16(X + (size_t)row * 192 + k0 + scc, &Xt[chb * 8]);
        gload_lds16(W + (size_t)(fb + row) * 192 + k0 + scc, &Wt[chb * 8]);
      }
      __syncthreads();
#pragma unroll
      for (int k2 = 0; k2 < 2; ++k2) {
        const int cco = k2 ? cc1 : cc0;
        bfrag8 a[4], b[4];
        for (int i = 0; i < 4; i++)
          a[i] = *(const bfrag8*)&Xt[(wr * 64 + i * 16 + lr) * 64 + cco];
        for (int j = 0; j < 4; j++)
          b[j] = *(const bfrag8*)&Wt[(wc * 64 + j * 16 + lr) * 64 + cco];
        for (int i = 0; i < 4; i++)
          for (int j = 0; j < 4; j++) acc[i][j] = mfma16(a[i], b[j], acc[i][j]);
      }
    }
    for (int j = 0; j < 4; j++) {
      int f = fb + wc * 64 + j * 16 + lr;
      float beta = beta2[n * 2048 + f];
      float w3f = w3[n * 2048 + f];
      for (int i = 0; i < 4; i++)
        for (int rg = 0; rg < 4; rg++) {
          float y = acc[i][j][rg] + beta;
          y = fmaxf(y, 0.f);
          rp[i][rg] += y * w3f;
        }
    }
  }
  for (int i = 0; i < 4; i++)
    for (int rg = 0; rg < 4; rg++) {
      float v = rp[i][rg];
      v += __shfl_xor(v, 1);
      v += __shfl_xor(v, 2);
      v += __shfl_xor(v, 4);
      v += __shfl_xor(v, 8);
      if (lr == 0) {
        int row = row0 + wr * 64 + i * 16 + lq * 4 + rg;
        atomicAdd(&r[n * 4608 + row], v);
      }
    }
}

// ---------------- K5: pair sum + bn3 + layer sum + final norm ----------------
__global__ void k_final(const float* __restrict__ r, const float* __restrict__ b3,
                        const float* __restrict__ g3, const float* __restrict__ bb3,
                        const float* __restrict__ ng, const float* __restrict__ nb,
                        float* __restrict__ out) {
  int p = blockIdx.x * 256 + threadIdx.x;
  if (p >= 2304) return;
  float acc = 0.f;
  for (int n = 0; n < 3; ++n) {
    float z = r[n * 4608 + 2 * p] + r[n * 4608 + 2 * p + 1] + 2.f * b3[n];
    acc += z * (g3[n] * BN_SCALE) + bb3[n];
  }
  out[p] = acc * (ng[0] * BN_SCALE) + nb[0];
}

extern "C" void kernel_launch(void* const* d_in, const int* in_sizes, int n_in,
                              void* d_out, int out_size, void* d_ws, size_t ws_size,
                              hipStream_t stream) {
  const float* memory = (const float*)d_in[0];
  const float* features = (const float*)d_in[1];
  const float* fc1_w = (const float*)d_in[2];
  const float* fc1_b = (const float*)d_in[3];
  const float* se = (const float*)d_in[4];
  const float* bn1_g = (const float*)d_in[5];
  const float* bn1_b = (const float*)d_in[6];
  const float* fc2_w = (const float*)d_in[7];
  const float* fc2_b = (const float*)d_in[8];
  const float* bn2_g = (const float*)d_in[9];
  const float* bn2_b = (const float*)d_in[10];
  const float* fc3_w = (const float*)d_in[11];
  const float* fc3_b = (const float*)d_in[12];
  const float* bn3_g = (const float*)d_in[13];
  const float* bn3_b = (const float*)d_in[14];
  const float* norm_g = (const float*)d_in[15];
  const float* norm_b = (const float*)d_in[16];

  char* ws = (char*)d_ws;
  float* gate = (float*)ws;                   // 442,368
  u16* w1B = (u16*)(ws + 442368);             // 1,572,864
  u16* w2B = (u16*)(ws + 2015232);            // 2,359,296
  float* beta2 = (float*)(ws + 4374528);      // 24,576
  u16* qB = (u16*)(ws + 4399104);             // 28,311,552
  u16* kB = (u16*)(ws + 32710656);            // 28,311,552
  u16* pooled = (u16*)(ws + 61022208);        // 5,308,416
  float* r = (float*)(ws + 66330624);         // 55,296  (total ~66.4 MB)

  hipFuncSetAttribute(reinterpret_cast<const void*>(k_score),
                      hipFuncAttributeMaxDynamicSharedMemorySize, 147456);

  hipMemsetAsync(r, 0, 3 * 4608 * sizeof(float), stream);
  k_prep<<<dim3(8136), 256, 0, stream>>>(se, gate, fc1_w, w1B, fc2_w, bn2_g,
                                         fc2_b, bn2_b, w2B, beta2);
  k_fc1<<<dim3(2, 72, 6), 256, 0, stream>>>(memory, features, w1B, fc1_b, qB, kB);
  k_score<<<dim3(1152, 3), 512, 147456, stream>>>(qB, kB, gate, bn1_g, bn1_b,
                                                  pooled);
  k_mlp<<<dim3(4, 36, 3), 256, 0, stream>>>(pooled, w2B, beta2, fc3_w, r);
  k_final<<<dim3(9), 256, 0, stream>>>(r, fc3_b, bn3_g, bn3_b, norm_g, norm_b,
                                       (float*)d_out);
}

// Round 7
// 561.369 us; speedup vs baseline: 1.2722x; 1.2722x over previous
//
#include <hip/hip_runtime.h>
#include <math.h>

#define BN_SCALE 0.9999950000374997f

typedef unsigned short u16;
typedef short bfrag8 __attribute__((ext_vector_type(8)));
typedef float floatx4 __attribute__((ext_vector_type(4)));

struct ushort4_t { u16 x, y, z, w; };

__device__ __forceinline__ u16 f2bf(float f) {
  union { float f; unsigned u; } c; c.f = f;
  unsigned r = c.u + 0x7FFFu + ((c.u >> 16) & 1u);
  return (u16)(r >> 16);
}

__device__ __forceinline__ void gload_lds16(const u16* g, u16* l) {
  __builtin_amdgcn_global_load_lds(
      (const __attribute__((address_space(1))) void*)g,
      (__attribute__((address_space(3))) void*)l, 16, 0, 0);
}

__device__ __forceinline__ floatx4 mfma16(bfrag8 a, bfrag8 b, floatx4 c) {
  return __builtin_amdgcn_mfma_f32_16x16x32_bf16(a, b, c, 0, 0, 0);
}

// qB/kB layout (u16): [n][tile(48)][kk(8)][row(192)][col(64)]
//   offset = ((n*48+tile)*8 + kk)*12288 + row*64 + col   (stored UNswizzled)
// gateP layout (f32): [n][wave(4)][vq(36)][lane(64)][e(4)]
//   vq = i*6+j, e = rg; value = sigmoid(se[n][s][t]) with
//   s = (w>>1)*96 + i*16 + (lane>>4)*4 + rg, t = (w&1)*96 + j*16 + (lane&15)

// ---------------- K0: prep — gateP (per-lane order), w2*alpha->bf16, beta2 ---------
__global__ void k_prep(const float* __restrict__ se, float* __restrict__ gateP,
                       const float* __restrict__ w2, const float* __restrict__ g2,
                       const float* __restrict__ b2, const float* __restrict__ bb2,
                       u16* __restrict__ w2B, float* __restrict__ beta2) {
  int idx = blockIdx.x * 256 + threadIdx.x;
  if (idx < 110592) {
    int e = idx & 3, lane = (idx >> 2) & 63;
    int rest = idx >> 8;              // (n*4 + w)*36 + vq
    int vq = rest % 36;
    int w = (rest / 36) & 3;
    int n = rest / 144;
    int i = vq / 6, j = vq - i * 6;
    int s = (w >> 1) * 96 + i * 16 + (lane >> 4) * 4 + e;
    int t = (w & 1) * 96 + j * 16 + (lane & 15);
    float x = se[n * 36864 + s * 192 + t];
    gateP[idx] = 1.0f / (1.0f + expf(-x));
    return;
  }
  idx -= 110592;
  if (idx < 1179648) {
    int nf = idx / 192;  // n*2048 + f
    w2B[idx] = f2bf(w2[idx] * (g2[nf] * BN_SCALE));
    return;
  }
  idx -= 1179648;
  if (idx < 6144) beta2[idx] = b2[idx] * (g2[idx] * BN_SCALE) + bb2[idx];
}

// ---------------- K2: fc1 GEMM  C[m,dout] = A[m,:].w1[dout,:] + b1 ----------------
// 128x128 tile, BK=64, f32 sources converted to bf16 into swizzled LDS.
// Output -> kk-tiled qB/kB layout.  acc[4][4] = 64 AGPR (no spill at 2 blocks/CU).
__global__ __launch_bounds__(256, 2) void k_fc1(
    const float* __restrict__ memin, const float* __restrict__ featin,
    const float* __restrict__ w1, const float* __restrict__ b1,
    u16* __restrict__ qB, u16* __restrict__ kB) {
  __shared__ __align__(16) u16 At[128 * 64];
  __shared__ __align__(16) u16 Bt[128 * 64];
  const int tid = threadIdx.x, lane = tid & 63, wave = tid >> 6;
  const int bz = blockIdx.z, n = bz >> 1, side = bz & 1;
  const int m0 = blockIdx.y * 128, n0 = blockIdx.x * 128;
  const float* A = (side ? featin : memin) + n * 512;   // ld 1536 f32
  const float* B = w1 + (size_t)n * 262144;             // ld 512 f32
  u16* Cn = (side ? kB : qB) + (size_t)n * 4718592;

  floatx4 acc[4][4];
  for (int i = 0; i < 4; i++)
    for (int j = 0; j < 4; j++) acc[i][j] = (floatx4){0.f, 0.f, 0.f, 0.f};
  const int wr = wave >> 1, wc = wave & 1;
  const int lr = lane & 15, lq = lane >> 4;
  const int sw = lr & 7;
  const int cc0 = (lq ^ sw) << 3, cc1 = ((lq + 4) ^ sw) << 3;

  for (int kk = 0; kk < 8; ++kk) {
    const int k0 = kk * 64;
    __syncthreads();
    // A & B: f32 -> bf16, one 16B LDS chunk per thread per it, source-swizzled
    for (int it = 0; it < 4; ++it) {
      int ch = it * 256 + tid;              // chunk in 128x64 tile
      int row = ch >> 3, cc = ch & 7;
      int scc = cc ^ (row & 7);
      const float* srcA = &A[(size_t)(m0 + row) * 1536 + k0 + scc * 8];
      float4 a0 = *(const float4*)srcA;
      float4 a1 = *(const float4*)(srcA + 4);
      ushort4_t h0 = {f2bf(a0.x), f2bf(a0.y), f2bf(a0.z), f2bf(a0.w)};
      ushort4_t h1 = {f2bf(a1.x), f2bf(a1.y), f2bf(a1.z), f2bf(a1.w)};
      *(ushort4_t*)&At[ch * 8] = h0;
      *(ushort4_t*)&At[ch * 8 + 4] = h1;
      const float* srcB = &B[(size_t)(n0 + row) * 512 + k0 + scc * 8];
      float4 b0 = *(const float4*)srcB;
      float4 b1v = *(const float4*)(srcB + 4);
      ushort4_t g0 = {f2bf(b0.x), f2bf(b0.y), f2bf(b0.z), f2bf(b0.w)};
      ushort4_t g1 = {f2bf(b1v.x), f2bf(b1v.y), f2bf(b1v.z), f2bf(b1v.w)};
      *(ushort4_t*)&Bt[ch * 8] = g0;
      *(ushort4_t*)&Bt[ch * 8 + 4] = g1;
    }
    __syncthreads();
#pragma unroll
    for (int k2 = 0; k2 < 2; ++k2) {
      const int cco = k2 ? cc1 : cc0;
      bfrag8 a[4], b[4];
      for (int i = 0; i < 4; i++)
        a[i] = *(const bfrag8*)&At[(wr * 64 + i * 16 + lr) * 64 + cco];
      for (int j = 0; j < 4; j++)
        b[j] = *(const bfrag8*)&Bt[(wc * 64 + j * 16 + lr) * 64 + cco];
      for (int i = 0; i < 4; i++)
        for (int j = 0; j < 4; j++) acc[i][j] = mfma16(a[i], b[j], acc[i][j]);
    }
  }
  for (int j = 0; j < 4; j++) {
    int col = n0 + wc * 64 + j * 16 + lr;
    float bias = b1[n * 512 + col];
    int kkd = col >> 6, cw = col & 63;
    for (int i = 0; i < 4; i++) {
      int rbase = m0 + wr * 64 + i * 16 + lq * 4;
      for (int rg = 0; rg < 4; rg++) {
        int rr = rbase + rg;
        int tile = rr / 192, rw = rr - tile * 192;
        Cn[((size_t)tile * 8 + kkd) * 12288 + rw * 64 + cw] =
            f2bf(acc[i][j][rg] + bias);
      }
    }
  }
}

// ---------------- K3: per (n,q,k): gated 192x192 score + dual max-pool + bn1 -------
// Round-2 proven structure: 4 waves, each 96x96 (acc[6][6]), 2 blocks/CU, static LDS,
// XOR-swizzled staging/reads.  NEW: gate read from gateP in per-lane coalesced order.
__global__ __launch_bounds__(256, 2) void k_score(
    const u16* __restrict__ qB, const u16* __restrict__ kB,
    const float* __restrict__ gateP,
    const float* __restrict__ bn1g, const float* __restrict__ bn1b,
    u16* __restrict__ pooled) {
  __shared__ __align__(16) u16 At[192 * 64];
  __shared__ __align__(16) u16 Bt[192 * 64];
  __shared__ float colL[8 * 192];
  __shared__ float rowL[2 * 192];
  const int tid = threadIdx.x, lane = tid & 63, wave = tid >> 6;
  const int lin = blockIdx.x, n = blockIdx.y;
  const int xcd = lin & 7, idx = lin >> 3;
  const int qIdx = idx / 6, kIdx = xcd * 6 + (idx - (idx / 6) * 6);
  const u16* A = kB + ((size_t)(n * 48 + kIdx) * 8) * 12288;
  const u16* Bp = qB + ((size_t)(n * 48 + qIdx) * 8) * 12288;
  const int ws = wave >> 1, wt = wave & 1;
  const int lr = lane & 15, lq = lane >> 4;
  const int sw = lr & 7;
  const int cc0 = (lq ^ sw) << 3;        // swizzled u16 col offset, k2=0
  const int cc1 = ((lq + 4) ^ sw) << 3;  // k2=32

  floatx4 acc[6][6];
  for (int i = 0; i < 6; i++)
    for (int j = 0; j < 6; j++) acc[i][j] = (floatx4){0.f, 0.f, 0.f, 0.f};

  for (int kk = 0; kk < 8; ++kk) {
    const u16* Akk = A + kk * 12288;
    const u16* Bkk = Bp + kk * 12288;
    __syncthreads();
    for (int it = 0; it < 6; ++it) {
      int chb = it * 256 + wave * 64;  // wave-uniform chunk base
      int ch = chb + lane;
      int row = ch >> 3, cc = ch & 7;
      int src = (row << 3) + (cc ^ (row & 7));  // swizzled source chunk
      gload_lds16(Akk + src * 8, &At[chb * 8]);
      gload_lds16(Bkk + src * 8, &Bt[chb * 8]);
    }
    __syncthreads();
#pragma unroll
    for (int k2 = 0; k2 < 2; ++k2) {
      const int cco = k2 ? cc1 : cc0;
      bfrag8 a[6], b[6];
      for (int i = 0; i < 6; i++)
        a[i] = *(const bfrag8*)&At[(ws * 96 + i * 16 + lr) * 64 + cco];
      for (int j = 0; j < 6; j++)
        b[j] = *(const bfrag8*)&Bt[(wt * 96 + j * 16 + lr) * 64 + cco];
      for (int i = 0; i < 6; i++)
        for (int j = 0; j < 6; j++) acc[i][j] = mfma16(a[i], b[j], acc[i][j]);
    }
  }

  // ---- gated dual max-pool; gate from gateP (coalesced float4 per (i,j)) ----
  const float* gp = gateP + ((size_t)(n * 4 + wave) * 36) * 256 + lane * 4;
  float colp[6], rowp[6][4];
  for (int j = 0; j < 6; j++) colp[j] = -INFINITY;
  for (int i = 0; i < 6; i++)
    for (int rg = 0; rg < 4; rg++) rowp[i][rg] = -INFINITY;
  for (int i = 0; i < 6; i++) {
    for (int j = 0; j < 6; j++) {
      float4 g = *(const float4*)(gp + (i * 6 + j) * 256);
      const float* gv = (const float*)&g;
      for (int rg = 0; rg < 4; rg++) {
        float v = acc[i][j][rg] * gv[rg];
        colp[j] = fmaxf(colp[j], v);
        rowp[i][rg] = fmaxf(rowp[i][rg], v);
      }
    }
  }
  for (int j = 0; j < 6; j++)
    colL[(ws * 4 + lq) * 192 + wt * 96 + j * 16 + lr] = colp[j];
  for (int i = 0; i < 6; i++)
    for (int rg = 0; rg < 4; rg++) {
      float v = rowp[i][rg];
      v = fmaxf(v, __shfl_xor(v, 1));
      v = fmaxf(v, __shfl_xor(v, 2));
      v = fmaxf(v, __shfl_xor(v, 4));
      v = fmaxf(v, __shfl_xor(v, 8));
      if (lr == 0) rowL[wt * 192 + ws * 96 + i * 16 + lq * 4 + rg] = v;
    }
  __syncthreads();

  const float g1 = bn1g[n] * BN_SCALE;
  const float bb1 = bn1b[n];
  u16* outp = pooled + ((size_t)n * 2304 + (size_t)qIdx * 48 + kIdx) * 384;
  for (int id = tid; id < 384; id += 256) {
    if (id < 192) {
      float m = colL[id];
      for (int w = 1; w < 8; w++) m = fmaxf(m, colL[w * 192 + id]);
      outp[id] = f2bf(m * g1 + bb1);
    } else {
      int s = id - 192;
      float m = fmaxf(rowL[s], rowL[192 + s]);
      outp[id] = f2bf(m * g1 + bb1);
    }
  }
}

// ---------------- K4: fused fc2(alpha-folded) + relu + fc3 partials ----------------
__global__ __launch_bounds__(256, 1) void k_mlp(
    const u16* __restrict__ pooled, const u16* __restrict__ w2B,
    const float* __restrict__ beta2, const float* __restrict__ w3,
    float* __restrict__ r) {
  __shared__ __align__(16) u16 Xt[128 * 64];
  __shared__ __align__(16) u16 Wt[128 * 64];
  const int tid = threadIdx.x, lane = tid & 63, wave = tid >> 6;
  const int n = blockIdx.z, row0 = blockIdx.y * 128, f0 = blockIdx.x * 512;
  const u16* X = pooled + ((size_t)n * 4608 + row0) * 192;  // ld 192 bf16
  const u16* W = w2B + (size_t)n * 2048 * 192;              // ld 192 bf16
  const int wr = wave >> 1, wc = wave & 1;
  const int lr = lane & 15, lq = lane >> 4;
  const int sw = lr & 7;
  const int cc0 = (lq ^ sw) << 3, cc1 = ((lq + 4) ^ sw) << 3;
  float rp[4][4];
  for (int i = 0; i < 4; i++)
    for (int rg = 0; rg < 4; rg++) rp[i][rg] = 0.f;

  for (int fs = 0; fs < 4; ++fs) {
    const int fb = f0 + fs * 128;
    floatx4 acc[4][4];
    for (int i = 0; i < 4; i++)
      for (int j = 0; j < 4; j++) acc[i][j] = (floatx4){0.f, 0.f, 0.f, 0.f};
    for (int kk = 0; kk < 3; ++kk) {
      const int k0 = kk * 64;
      __syncthreads();
      for (int it = 0; it < 4; ++it) {
        int chb = it * 256 + wave * 64;
        int ch = chb + lane;
        int row = ch >> 3, cc = ch & 7;
        int scc = (cc ^ (row & 7)) << 3;
        gload_lds16(X + (size_t)row * 192 + k0 + scc, &Xt[chb * 8]);
        gload_lds16(W + (size_t)(fb + row) * 192 + k0 + scc, &Wt[chb * 8]);
      }
      __syncthreads();
#pragma unroll
      for (int k2 = 0; k2 < 2; ++k2) {
        const int cco = k2 ? cc1 : cc0;
        bfrag8 a[4], b[4];
        for (int i = 0; i < 4; i++)
          a[i] = *(const bfrag8*)&Xt[(wr * 64 + i * 16 + lr) * 64 + cco];
        for (int j = 0; j < 4; j++)
          b[j] = *(const bfrag8*)&Wt[(wc * 64 + j * 16 + lr) * 64 + cco];
        for (int i = 0; i < 4; i++)
          for (int j = 0; j < 4; j++) acc[i][j] = mfma16(a[i], b[j], acc[i][j]);
      }
    }
    for (int j = 0; j < 4; j++) {
      int f = fb + wc * 64 + j * 16 + lr;
      float beta = beta2[n * 2048 + f];
      float w3f = w3[n * 2048 + f];
      for (int i = 0; i < 4; i++)
        for (int rg = 0; rg < 4; rg++) {
          float y = acc[i][j][rg] + beta;
          y = fmaxf(y, 0.f);
          rp[i][rg] += y * w3f;
        }
    }
  }
  for (int i = 0; i < 4; i++)
    for (int rg = 0; rg < 4; rg++) {
      float v = rp[i][rg];
      v += __shfl_xor(v, 1);
      v += __shfl_xor(v, 2);
      v += __shfl_xor(v, 4);
      v += __shfl_xor(v, 8);
      if (lr == 0) {
        int row = row0 + wr * 64 + i * 16 + lq * 4 + rg;
        atomicAdd(&r[n * 4608 + row], v);
      }
    }
}

// ---------------- K5: pair sum + bn3 + layer sum + final norm ----------------
__global__ void k_final(const float* __restrict__ r, const float* __restrict__ b3,
                        const float* __restrict__ g3, const float* __restrict__ bb3,
                        const float* __restrict__ ng, const float* __restrict__ nb,
                        float* __restrict__ out) {
  int p = blockIdx.x * 256 + threadIdx.x;
  if (p >= 2304) return;
  float acc = 0.f;
  for (int n = 0; n < 3; ++n) {
    float z = r[n * 4608 + 2 * p] + r[n * 4608 + 2 * p + 1] + 2.f * b3[n];
    acc += z * (g3[n] * BN_SCALE) + bb3[n];
  }
  out[p] = acc * (ng[0] * BN_SCALE) + nb[0];
}

extern "C" void kernel_launch(void* const* d_in, const int* in_sizes, int n_in,
                              void* d_out, int out_size, void* d_ws, size_t ws_size,
                              hipStream_t stream) {
  const float* memory = (const float*)d_in[0];
  const float* features = (const float*)d_in[1];
  const float* fc1_w = (const float*)d_in[2];
  const float* fc1_b = (const float*)d_in[3];
  const float* se = (const float*)d_in[4];
  const float* bn1_g = (const float*)d_in[5];
  const float* bn1_b = (const float*)d_in[6];
  const float* fc2_w = (const float*)d_in[7];
  const float* fc2_b = (const float*)d_in[8];
  const float* bn2_g = (const float*)d_in[9];
  const float* bn2_b = (const float*)d_in[10];
  const float* fc3_w = (const float*)d_in[11];
  const float* fc3_b = (const float*)d_in[12];
  const float* bn3_g = (const float*)d_in[13];
  const float* bn3_b = (const float*)d_in[14];
  const float* norm_g = (const float*)d_in[15];
  const float* norm_b = (const float*)d_in[16];

  char* ws = (char*)d_ws;
  float* gateP = (float*)ws;                  // 442,368
  u16* w2B = (u16*)(ws + 442368);             // 2,359,296
  float* beta2 = (float*)(ws + 2801664);      // 24,576
  u16* qB = (u16*)(ws + 2826240);             // 28,311,552
  u16* kB = (u16*)(ws + 31137792);            // 28,311,552
  u16* pooled = (u16*)(ws + 59449344);        // 5,308,416
  float* r = (float*)(ws + 64757760);         // 55,296  (total ~64.8 MB)

  hipMemsetAsync(r, 0, 3 * 4608 * sizeof(float), stream);
  k_prep<<<dim3(5064), 256, 0, stream>>>(se, gateP, fc2_w, bn2_g, fc2_b, bn2_b,
                                         w2B, beta2);
  k_fc1<<<dim3(4, 72, 6), 256, 0, stream>>>(memory, features, fc1_w, fc1_b, qB, kB);
  k_score<<<dim3(2304, 3), 256, 0, stream>>>(qB, kB, gateP, bn1_g, bn1_b, pooled);
  k_mlp<<<dim3(4, 36, 3), 256, 0, stream>>>(pooled, w2B, beta2, fc3_w, r);
  k_final<<<dim3(9), 256, 0, stream>>>(r, fc3_b, bn3_g, bn3_b, norm_g, norm_b,
                                       (float*)d_out);
}

// Round 8
// 499.801 us; speedup vs baseline: 1.4289x; 1.1232x over previous
//
#include <hip/hip_runtime.h>
#include <math.h>

#define BN_SCALE 0.9999950000374997f

typedef unsigned short u16;
typedef short bfrag8 __attribute__((ext_vector_type(8)));
typedef float floatx4 __attribute__((ext_vector_type(4)));

struct ushort4_t { u16 x, y, z, w; };

__device__ __forceinline__ u16 f2bf(float f) {
  union { float f; unsigned u; } c; c.f = f;
  unsigned r = c.u + 0x7FFFu + ((c.u >> 16) & 1u);
  return (u16)(r >> 16);
}

__device__ __forceinline__ void gload_lds16(const u16* g, u16* l) {
  __builtin_amdgcn_global_load_lds(
      (const __attribute__((address_space(1))) void*)g,
      (__attribute__((address_space(3))) void*)l, 16, 0, 0);
}

__device__ __forceinline__ floatx4 mfma16(bfrag8 a, bfrag8 b, floatx4 c) {
  return __builtin_amdgcn_mfma_f32_16x16x32_bf16(a, b, c, 0, 0, 0);
}

// qB/kB layout (u16): [n][tile(48)][kk(8)][row(192)][col(64)]
//   offset = ((n*48+tile)*8 + kk)*12288 + row*64 + col   (stored UNswizzled)
// gateP layout (f32): [n][wave(4)][vq(36)][lane(64)][e(4)]  (r7-verified)

// ---------------- K0: prep — gateP, w1->bf16, w2*alpha->bf16, beta2 ----------------
__global__ void k_prep(const float* __restrict__ se, float* __restrict__ gateP,
                       const float* __restrict__ w1, u16* __restrict__ w1B,
                       const float* __restrict__ w2, const float* __restrict__ g2,
                       const float* __restrict__ b2, const float* __restrict__ bb2,
                       u16* __restrict__ w2B, float* __restrict__ beta2) {
  int idx = blockIdx.x * 256 + threadIdx.x;
  if (idx < 110592) {
    int e = idx & 3, lane = (idx >> 2) & 63;
    int rest = idx >> 8;              // (n*4 + w)*36 + vq
    int vq = rest % 36;
    int w = (rest / 36) & 3;
    int n = rest / 144;
    int i = vq / 6, j = vq - i * 6;
    int s = (w >> 1) * 96 + i * 16 + (lane >> 4) * 4 + e;
    int t = (w & 1) * 96 + j * 16 + (lane & 15);
    float x = se[n * 36864 + s * 192 + t];
    gateP[idx] = 1.0f / (1.0f + expf(-x));
    return;
  }
  idx -= 110592;
  if (idx < 786432) {
    w1B[idx] = f2bf(w1[idx]);
    return;
  }
  idx -= 786432;
  if (idx < 1179648) {
    int nf = idx / 192;  // n*2048 + f
    w2B[idx] = f2bf(w2[idx] * (g2[nf] * BN_SCALE));
    return;
  }
  idx -= 1179648;
  if (idx < 6144) beta2[idx] = b2[idx] * (g2[idx] * BN_SCALE) + bb2[idx];
}

// ---------------- K2: fc1 GEMM  C[m,dout] = A[m,:].w1[dout,:] + b1 ----------------
// 128x128 tile, BK=64. A: f32->bf16 inline convert; B: bf16 w1B via global_load_lds.
// Epilogue: acc -> LDS 128x128 bf16 tile (XOR-swizzled) -> coalesced 16B stores into
// the kk-tiled qB/kB layout (fixes the 2-byte-scatter write pathology).
__global__ __launch_bounds__(256, 2) void k_fc1(
    const float* __restrict__ memin, const float* __restrict__ featin,
    const u16* __restrict__ w1B, const float* __restrict__ b1,
    u16* __restrict__ qB, u16* __restrict__ kB) {
  __shared__ __align__(16) u16 T[128 * 128];  // staging: A=T[0:8192], B=T[8192:16384]
  u16* At = T;
  u16* Bt = T + 8192;
  const int tid = threadIdx.x, lane = tid & 63, wave = tid >> 6;
  const int bz = blockIdx.z, n = bz >> 1, side = bz & 1;
  const int m0 = blockIdx.y * 128, n0 = blockIdx.x * 128;
  const float* A = (side ? featin : memin) + n * 512;   // ld 1536 f32
  const u16* B = w1B + (size_t)n * 262144;              // ld 512 bf16
  u16* Cn = (side ? kB : qB) + (size_t)n * 4718592;

  floatx4 acc[4][4];
  for (int i = 0; i < 4; i++)
    for (int j = 0; j < 4; j++) acc[i][j] = (floatx4){0.f, 0.f, 0.f, 0.f};
  const int wr = wave >> 1, wc = wave & 1;
  const int lr = lane & 15, lq = lane >> 4;
  const int sw = lr & 7;
  const int cc0 = (lq ^ sw) << 3, cc1 = ((lq + 4) ^ sw) << 3;

  for (int kk = 0; kk < 8; ++kk) {
    const int k0 = kk * 64;
    __syncthreads();
    // B: async bf16 staging, source-swizzled (issue first: stays in flight)
    for (int it = 0; it < 4; ++it) {
      int chb = it * 256 + wave * 64;
      int ch = chb + lane;
      int row = ch >> 3, cc = ch & 7;
      int scc = cc ^ (row & 7);
      gload_lds16(B + (size_t)(n0 + row) * 512 + k0 + scc * 8, &Bt[chb * 8]);
    }
    // A: f32 -> bf16 inline, one 16B chunk per thread per it
    for (int it = 0; it < 4; ++it) {
      int ch = it * 256 + tid;              // chunk in 128x64 tile
      int row = ch >> 3, cc = ch & 7;
      int scc = cc ^ (row & 7);
      const float* srcA = &A[(size_t)(m0 + row) * 1536 + k0 + scc * 8];
      float4 a0 = *(const float4*)srcA;
      float4 a1 = *(const float4*)(srcA + 4);
      ushort4_t h0 = {f2bf(a0.x), f2bf(a0.y), f2bf(a0.z), f2bf(a0.w)};
      ushort4_t h1 = {f2bf(a1.x), f2bf(a1.y), f2bf(a1.z), f2bf(a1.w)};
      *(ushort4_t*)&At[ch * 8] = h0;
      *(ushort4_t*)&At[ch * 8 + 4] = h1;
    }
    __syncthreads();
#pragma unroll
    for (int k2 = 0; k2 < 2; ++k2) {
      const int cco = k2 ? cc1 : cc0;
      bfrag8 a[4], b[4];
      for (int i = 0; i < 4; i++)
        a[i] = *(const bfrag8*)&At[(wr * 64 + i * 16 + lr) * 64 + cco];
      for (int j = 0; j < 4; j++)
        b[j] = *(const bfrag8*)&Bt[(wc * 64 + j * 16 + lr) * 64 + cco];
      for (int i = 0; i < 4; i++)
        for (int j = 0; j < 4; j++) acc[i][j] = mfma16(a[i], b[j], acc[i][j]);
    }
  }

  // ---- epilogue: acc -> LDS (bf16, XOR-swizzled 16-chunk rows) ----
  __syncthreads();
  for (int j = 0; j < 4; j++) {
    int col = wc * 64 + j * 16 + lr;
    float bias = b1[n * 512 + n0 + col];
    int c = col >> 3, e = col & 7;
    for (int i = 0; i < 4; i++) {
      int rbase = wr * 64 + i * 16 + lq * 4;
      for (int rg = 0; rg < 4; rg++) {
        int row = rbase + rg;
        T[row * 128 + (c ^ (row & 15)) * 8 + e] = f2bf(acc[i][j][rg] + bias);
      }
    }
  }
  __syncthreads();
  // ---- coalesced read-out: 2048 16B chunks -> kk-tiled global layout ----
  for (int it = 0; it < 8; ++it) {
    int ch = it * 256 + tid;
    int row = ch >> 4, c = ch & 15;
    int colg = n0 + c * 8;
    int kkd = colg >> 6, cw = colg & 63;
    int rr = m0 + row;
    int tile = rr / 192, rw = rr - tile * 192;
    *(uint4*)&Cn[((size_t)tile * 8 + kkd) * 12288 + rw * 64 + cw] =
        *(const uint4*)&T[row * 128 + (c ^ (row & 15)) * 8];
  }
}

// ---------------- K3: per (n,q,k): gated 192x192 score + dual max-pool + bn1 -------
// r7-proven: 4 waves, 96x96/wave (acc[6][6]), 2 blocks/CU, XOR-swizzled LDS, gateP.
__global__ __launch_bounds__(256, 2) void k_score(
    const u16* __restrict__ qB, const u16* __restrict__ kB,
    const float* __restrict__ gateP,
    const float* __restrict__ bn1g, const float* __restrict__ bn1b,
    u16* __restrict__ pooled) {
  __shared__ __align__(16) u16 At[192 * 64];
  __shared__ __align__(16) u16 Bt[192 * 64];
  __shared__ float colL[8 * 192];
  __shared__ float rowL[2 * 192];
  const int tid = threadIdx.x, lane = tid & 63, wave = tid >> 6;
  const int lin = blockIdx.x, n = blockIdx.y;
  const int xcd = lin & 7, idx = lin >> 3;
  const int qIdx = idx / 6, kIdx = xcd * 6 + (idx - (idx / 6) * 6);
  const u16* A = kB + ((size_t)(n * 48 + kIdx) * 8) * 12288;
  const u16* Bp = qB + ((size_t)(n * 48 + qIdx) * 8) * 12288;
  const int ws = wave >> 1, wt = wave & 1;
  const int lr = lane & 15, lq = lane >> 4;
  const int sw = lr & 7;
  const int cc0 = (lq ^ sw) << 3;        // swizzled u16 col offset, k2=0
  const int cc1 = ((lq + 4) ^ sw) << 3;  // k2=32

  floatx4 acc[6][6];
  for (int i = 0; i < 6; i++)
    for (int j = 0; j < 6; j++) acc[i][j] = (floatx4){0.f, 0.f, 0.f, 0.f};

  for (int kk = 0; kk < 8; ++kk) {
    const u16* Akk = A + kk * 12288;
    const u16* Bkk = Bp + kk * 12288;
    __syncthreads();
    for (int it = 0; it < 6; ++it) {
      int chb = it * 256 + wave * 64;  // wave-uniform chunk base
      int ch = chb + lane;
      int row = ch >> 3, cc = ch & 7;
      int src = (row << 3) + (cc ^ (row & 7));  // swizzled source chunk
      gload_lds16(Akk + src * 8, &At[chb * 8]);
      gload_lds16(Bkk + src * 8, &Bt[chb * 8]);
    }
    __syncthreads();
#pragma unroll
    for (int k2 = 0; k2 < 2; ++k2) {
      const int cco = k2 ? cc1 : cc0;
      bfrag8 a[6], b[6];
      for (int i = 0; i < 6; i++)
        a[i] = *(const bfrag8*)&At[(ws * 96 + i * 16 + lr) * 64 + cco];
      for (int j = 0; j < 6; j++)
        b[j] = *(const bfrag8*)&Bt[(wt * 96 + j * 16 + lr) * 64 + cco];
      for (int i = 0; i < 6; i++)
        for (int j = 0; j < 6; j++) acc[i][j] = mfma16(a[i], b[j], acc[i][j]);
    }
  }

  // ---- gated dual max-pool; gate from gateP (coalesced float4 per (i,j)) ----
  const float* gp = gateP + ((size_t)(n * 4 + wave) * 36) * 256 + lane * 4;
  float colp[6], rowp[6][4];
  for (int j = 0; j < 6; j++) colp[j] = -INFINITY;
  for (int i = 0; i < 6; i++)
    for (int rg = 0; rg < 4; rg++) rowp[i][rg] = -INFINITY;
  for (int i = 0; i < 6; i++) {
    for (int j = 0; j < 6; j++) {
      float4 g = *(const float4*)(gp + (i * 6 + j) * 256);
      const float* gv = (const float*)&g;
      for (int rg = 0; rg < 4; rg++) {
        float v = acc[i][j][rg] * gv[rg];
        colp[j] = fmaxf(colp[j], v);
        rowp[i][rg] = fmaxf(rowp[i][rg], v);
      }
    }
  }
  for (int j = 0; j < 6; j++)
    colL[(ws * 4 + lq) * 192 + wt * 96 + j * 16 + lr] = colp[j];
  for (int i = 0; i < 6; i++)
    for (int rg = 0; rg < 4; rg++) {
      float v = rowp[i][rg];
      v = fmaxf(v, __shfl_xor(v, 1));
      v = fmaxf(v, __shfl_xor(v, 2));
      v = fmaxf(v, __shfl_xor(v, 4));
      v = fmaxf(v, __shfl_xor(v, 8));
      if (lr == 0) rowL[wt * 192 + ws * 96 + i * 16 + lq * 4 + rg] = v;
    }
  __syncthreads();

  const float g1 = bn1g[n] * BN_SCALE;
  const float bb1 = bn1b[n];
  u16* outp = pooled + ((size_t)n * 2304 + (size_t)qIdx * 48 + kIdx) * 384;
  for (int id = tid; id < 384; id += 256) {
    if (id < 192) {
      float m = colL[id];
      for (int w = 1; w < 8; w++) m = fmaxf(m, colL[w * 192 + id]);
      outp[id] = f2bf(m * g1 + bb1);
    } else {
      int s = id - 192;
      float m = fmaxf(rowL[s], rowL[192 + s]);
      outp[id] = f2bf(m * g1 + bb1);
    }
  }
}

// ---------------- K4: fused fc2(alpha-folded) + relu + fc3 partials ----------------
// grid (16, 36, 3): one 128-f chunk per block -> 1728 blocks (fills 256 CUs).
__global__ __launch_bounds__(256, 2) void k_mlp(
    const u16* __restrict__ pooled, const u16* __restrict__ w2B,
    const float* __restrict__ beta2, const float* __restrict__ w3,
    float* __restrict__ r) {
  __shared__ __align__(16) u16 Xt[128 * 64];
  __shared__ __align__(16) u16 Wt[128 * 64];
  const int tid = threadIdx.x, lane = tid & 63, wave = tid >> 6;
  const int n = blockIdx.z, row0 = blockIdx.y * 128, fb = blockIdx.x * 128;
  const u16* X = pooled + ((size_t)n * 4608 + row0) * 192;  // ld 192 bf16
  const u16* W = w2B + (size_t)n * 2048 * 192;              // ld 192 bf16
  const int wr = wave >> 1, wc = wave & 1;
  const int lr = lane & 15, lq = lane >> 4;
  const int sw = lr & 7;
  const int cc0 = (lq ^ sw) << 3, cc1 = ((lq + 4) ^ sw) << 3;

  floatx4 acc[4][4];
  for (int i = 0; i < 4; i++)
    for (int j = 0; j < 4; j++) acc[i][j] = (floatx4){0.f, 0.f, 0.f, 0.f};
  for (int kk = 0; kk < 3; ++kk) {
    const int k0 = kk * 64;
    __syncthreads();
    for (int it = 0; it < 4; ++it) {
      int chb = it * 256 + wave * 64;
      int ch = chb + lane;
      int row = ch >> 3, cc = ch & 7;
      int scc = (cc ^ (row & 7)) << 3;
      gload_lds16(X + (size_t)row * 192 + k0 + scc, &Xt[chb * 8]);
      gload_lds16(W + (size_t)(fb + row) * 192 + k0 + scc, &Wt[chb * 8]);
    }
    __syncthreads();
#pragma unroll
    for (int k2 = 0; k2 < 2; ++k2) {
      const int cco = k2 ? cc1 : cc0;
      bfrag8 a[4], b[4];
      for (int i = 0; i < 4; i++)
        a[i] = *(const bfrag8*)&Xt[(wr * 64 + i * 16 + lr) * 64 + cco];
      for (int j = 0; j < 4; j++)
        b[j] = *(const bfrag8*)&Wt[(wc * 64 + j * 16 + lr) * 64 + cco];
      for (int i = 0; i < 4; i++)
        for (int j = 0; j < 4; j++) acc[i][j] = mfma16(a[i], b[j], acc[i][j]);
    }
  }
  float rp[4][4];
  for (int i = 0; i < 4; i++)
    for (int rg = 0; rg < 4; rg++) rp[i][rg] = 0.f;
  for (int j = 0; j < 4; j++) {
    int f = fb + wc * 64 + j * 16 + lr;
    float beta = beta2[n * 2048 + f];
    float w3f = w3[n * 2048 + f];
    for (int i = 0; i < 4; i++)
      for (int rg = 0; rg < 4; rg++) {
        float y = acc[i][j][rg] + beta;
        y = fmaxf(y, 0.f);
        rp[i][rg] += y * w3f;
      }
  }
  for (int i = 0; i < 4; i++)
    for (int rg = 0; rg < 4; rg++) {
      float v = rp[i][rg];
      v += __shfl_xor(v, 1);
      v += __shfl_xor(v, 2);
      v += __shfl_xor(v, 4);
      v += __shfl_xor(v, 8);
      if (lr == 0) {
        int row = row0 + wr * 64 + i * 16 + lq * 4 + rg;
        atomicAdd(&r[n * 4608 + row], v);
      }
    }
}

// ---------------- K5: pair sum + bn3 + layer sum + final norm ----------------
__global__ void k_final(const float* __restrict__ r, const float* __restrict__ b3,
                        const float* __restrict__ g3, const float* __restrict__ bb3,
                        const float* __restrict__ ng, const float* __restrict__ nb,
                        float* __restrict__ out) {
  int p = blockIdx.x * 256 + threadIdx.x;
  if (p >= 2304) return;
  float acc = 0.f;
  for (int n = 0; n < 3; ++n) {
    float z = r[n * 4608 + 2 * p] + r[n * 4608 + 2 * p + 1] + 2.f * b3[n];
    acc += z * (g3[n] * BN_SCALE) + bb3[n];
  }
  out[p] = acc * (ng[0] * BN_SCALE) + nb[0];
}

extern "C" void kernel_launch(void* const* d_in, const int* in_sizes, int n_in,
                              void* d_out, int out_size, void* d_ws, size_t ws_size,
                              hipStream_t stream) {
  const float* memory = (const float*)d_in[0];
  const float* features = (const float*)d_in[1];
  const float* fc1_w = (const float*)d_in[2];
  const float* fc1_b = (const float*)d_in[3];
  const float* se = (const float*)d_in[4];
  const float* bn1_g = (const float*)d_in[5];
  const float* bn1_b = (const float*)d_in[6];
  const float* fc2_w = (const float*)d_in[7];
  const float* fc2_b = (const float*)d_in[8];
  const float* bn2_g = (const float*)d_in[9];
  const float* bn2_b = (const float*)d_in[10];
  const float* fc3_w = (const float*)d_in[11];
  const float* fc3_b = (const float*)d_in[12];
  const float* bn3_g = (const float*)d_in[13];
  const float* bn3_b = (const float*)d_in[14];
  const float* norm_g = (const float*)d_in[15];
  const float* norm_b = (const float*)d_in[16];

  char* ws = (char*)d_ws;
  float* gateP = (float*)ws;                  // 442,368
  u16* w1B = (u16*)(ws + 442368);             // 1,572,864
  u16* w2B = (u16*)(ws + 2015232);            // 2,359,296
  float* beta2 = (float*)(ws + 4374528);      // 24,576
  u16* qB = (u16*)(ws + 4399104);             // 28,311,552
  u16* kB = (u16*)(ws + 32710656);            // 28,311,552
  u16* pooled = (u16*)(ws + 61022208);        // 5,308,416
  float* r = (float*)(ws + 66330624);         // 55,296  (total ~66.4 MB)

  hipMemsetAsync(r, 0, 3 * 4608 * sizeof(float), stream);
  k_prep<<<dim3(8136), 256, 0, stream>>>(se, gateP, fc1_w, w1B, fc2_w, bn2_g,
                                         fc2_b, bn2_b, w2B, beta2);
  k_fc1<<<dim3(4, 72, 6), 256, 0, stream>>>(memory, features, w1B, fc1_b, qB, kB);
  k_score<<<dim3(2304, 3), 256, 0, stream>>>(qB, kB, gateP, bn1_g, bn1_b, pooled);
  k_mlp<<<dim3(16, 36, 3), 256, 0, stream>>>(pooled, w2B, beta2, fc3_w, r);
  k_final<<<dim3(9), 256, 0, stream>>>(r, fc3_b, bn3_g, bn3_b, norm_g, norm_b,
                                       (float*)d_out);
}